// Round 3
// baseline (657.621 us; speedup 1.0000x reference)
//
#include <hip/hip_runtime.h>

// FMoELinearProj — R3: pre-convert to bf16 + two m97-style GEMMs.
// vs R2: (1) gemm1 epilogue repacks the 128x128 bf16 tile through LDS and
// stores Y with coalesced short8 (R2 did 64 scalar 2B stores/thread);
// (2) gemm2 split-K=4 -> 1024 blocks (3/CU resident vs 2); (3) gemm2 slot
// order (k,n,m) so C-tile m-sharers are schedule-adjacent on one XCD.

#define NEXP 16
#define TTOK 8192
#define DIN  1024
#define DOUT 4096
#define SDIM 512
#define LDSS 40   // fallback-path LDS stride
#define RPS  132  // repack row stride (ushorts): 128+4 -> quad rows land on distinct bank octets

typedef short short8 __attribute__((ext_vector_type(8)));
typedef float floatx4 __attribute__((ext_vector_type(4)));
typedef unsigned short ushort_t;

__device__ __forceinline__ ushort_t f2bf(float f) {
    union { float f; unsigned u; } v; v.f = f;
    unsigned r = v.u + 0x7FFFu + ((v.u >> 16) & 1u);   // RNE
    return (ushort_t)(r >> 16);
}

#define GLL16(g, l) __builtin_amdgcn_global_load_lds( \
    (const __attribute__((address_space(1))) void*)(g), \
    (__attribute__((address_space(3))) void*)(l), 16, 0, 0)

// ---------------- fp32 -> bf16 streaming convert ----------------
__global__ __launch_bounds__(256)
void cvt_kernel(const float* __restrict__ src, ushort_t* __restrict__ dst, int n8) {
    const int i = blockIdx.x * 256 + threadIdx.x;
    if (i >= n8) return;
    const float4 a = ((const float4*)src)[2 * i];
    const float4 b = ((const float4*)src)[2 * i + 1];
    short8 o;
    o[0] = (short)f2bf(a.x); o[1] = (short)f2bf(a.y);
    o[2] = (short)f2bf(a.z); o[3] = (short)f2bf(a.w);
    o[4] = (short)f2bf(b.x); o[5] = (short)f2bf(b.y);
    o[6] = (short)f2bf(b.z); o[7] = (short)f2bf(b.w);
    ((short8*)dst)[i] = o;
}

// ---------------- GEMM1: Y = bf16(Xb @ Wb_e^T + bias) ----------------
__global__ __launch_bounds__(256, 3)
void gemm1_f(const ushort_t* __restrict__ Xb, const int* __restrict__ counts,
             const ushort_t* __restrict__ Wb, const float* __restrict__ bias,
             ushort_t* __restrict__ Y) {
    __shared__ __align__(16) ushort_t smem[8448];   // As(4096) + Bs(4096); reused as 64x132 repack
    ushort_t* As = smem;
    ushort_t* Bs = smem + 4096;

    // XCD swizzle: 2048 blocks -> 8 XCDs x 256 slots; m fastest (W-tile sharers adjacent)
    const int l = ((blockIdx.x & 7) << 8) | (blockIdx.x >> 3);
    const int e = l >> 7;
    const int r = l & 127;
    const int n_tile = r >> 2, m_tile = r & 3;

    int off = 0;
    for (int i = 0; i < e; ++i) off += counts[i];
    const int cnt = counts[e];

    const int t = threadIdx.x, wave = t >> 6, lane = t & 63;
    const int wm = (wave & 1) << 6, wn = (wave >> 1) << 6;
    const int l15 = lane & 15, quad = lane >> 4;

    // staging: chunk c = 16 rows; lane -> row c*16+(lane>>2), granule slot lane&3
    // stored logical k-granule g = slot ^ ((row>>1)&3)
    const int g = (lane & 3) ^ ((lane >> 3) & 3);
    const int c0 = wave * 2, c1 = wave * 2 + 1;
    const int ar0 = c0 * 16 + (lane >> 2), ar1 = c1 * 16 + (lane >> 2);
    int xr0 = off + (m_tile << 7) + ar0; if (xr0 >= TTOK) xr0 = TTOK - 1;
    int xr1 = off + (m_tile << 7) + ar1; if (xr1 >= TTOK) xr1 = TTOK - 1;
    const ushort_t* gA0 = Xb + (size_t)xr0 * DIN + g * 8;
    const ushort_t* gA1 = Xb + (size_t)xr1 * DIN + g * 8;
    const ushort_t* Wp = Wb + (size_t)e * DOUT * DIN + (size_t)(n_tile << 7) * DIN;
    const ushort_t* gB0 = Wp + (size_t)ar0 * DIN + g * 8;
    const ushort_t* gB1 = Wp + (size_t)ar1 * DIN + g * 8;
    ushort_t* lA0 = As + c0 * 512; ushort_t* lA1 = As + c1 * 512;
    ushort_t* lB0 = Bs + c0 * 512; ushort_t* lB1 = Bs + c1 * 512;

    const int sw = (quad ^ ((l15 >> 1) & 3)) << 3;   // ds_read granule (elems)

    floatx4 acc[4][4] = {};

    for (int k0 = 0; k0 < DIN; k0 += 32) {
        GLL16(gA0, lA0); GLL16(gA1, lA1);
        GLL16(gB0, lB0); GLL16(gB1, lB1);
        gA0 += 32; gA1 += 32; gB0 += 32; gB1 += 32;
        __syncthreads();
        short8 af[4], bfr[4];
        #pragma unroll
        for (int i = 0; i < 4; ++i) {
            af[i]  = *(const short8*)&As[(wm + (i << 4) + l15) * 32 + sw];
            bfr[i] = *(const short8*)&Bs[(wn + (i << 4) + l15) * 32 + sw];
        }
        #pragma unroll
        for (int mi = 0; mi < 4; ++mi)
            #pragma unroll
            for (int ni = 0; ni < 4; ++ni)
                acc[mi][ni] = __builtin_amdgcn_mfma_f32_16x16x32_bf16(
                    af[mi], bfr[ni], acc[mi][ni], 0, 0, 0);
        __syncthreads();
    }

    float bv[4];
    #pragma unroll
    for (int ni = 0; ni < 4; ++ni)
        bv[ni] = bias[e * DOUT + (n_tile << 7) + wn + (ni << 4) + l15];

    // epilogue: per 64-row half, scatter bf16 into LDS then coalesced short8 store
    const int hsel = wm >> 6;
    #pragma unroll
    for (int h = 0; h < 2; ++h) {
        __syncthreads();
        if (hsel == h) {
            #pragma unroll
            for (int mi = 0; mi < 4; ++mi)
                #pragma unroll
                for (int ni = 0; ni < 4; ++ni)
                    #pragma unroll
                    for (int rg = 0; rg < 4; ++rg) {
                        const int rr = (mi << 4) + (quad << 2) + rg;       // 0..63
                        smem[rr * RPS + wn + (ni << 4) + l15] =
                            f2bf(acc[mi][ni][rg] + bv[ni]);
                    }
        }
        __syncthreads();
        #pragma unroll
        for (int p = 0; p < 4; ++p) {
            const int chunk = (p << 8) + t;         // 0..1023
            const int rr = chunk >> 4;              // 0..63
            const int cc = (chunk & 15) << 3;       // 0..120
            const int lrow = (m_tile << 7) + (h << 6) + rr;
            if (lrow < cnt)
                *(short8*)(Y + (size_t)(off + lrow) * DOUT + (n_tile << 7) + cc)
                    = *(const short8*)&smem[rr * RPS + cc];
        }
    }
}

// ---------------- GEMM2: P[ks] = Y @ Cb_e^T over K-quarter ----------------
__global__ __launch_bounds__(256, 3)
void gemm2_f(const ushort_t* __restrict__ Y, const int* __restrict__ counts,
             const ushort_t* __restrict__ Cb, float* __restrict__ P) {
    __shared__ __align__(16) ushort_t smem[8192];
    ushort_t* As = smem;
    ushort_t* Bs = smem + 4096;

    // 1024 blocks -> 8 XCDs x 128 slots; slot order (e, kslice, n, m)
    const int l = ((blockIdx.x & 7) << 7) | (blockIdx.x >> 3);
    const int e = l >> 6;
    const int r = l & 63;
    const int kslice = r >> 4;
    const int n_tile = (r >> 2) & 3;
    const int m_tile = r & 3;

    int off = 0;
    for (int i = 0; i < e; ++i) off += counts[i];
    const int cnt = counts[e];

    const int t = threadIdx.x, wave = t >> 6, lane = t & 63;
    const int wm = (wave & 1) << 6, wn = (wave >> 1) << 6;
    const int l15 = lane & 15, quad = lane >> 4;

    const int g = (lane & 3) ^ ((lane >> 3) & 3);
    const int c0 = wave * 2, c1 = wave * 2 + 1;
    const int ar0 = c0 * 16 + (lane >> 2), ar1 = c1 * 16 + (lane >> 2);
    int yr0 = off + (m_tile << 7) + ar0; if (yr0 >= TTOK) yr0 = TTOK - 1;
    int yr1 = off + (m_tile << 7) + ar1; if (yr1 >= TTOK) yr1 = TTOK - 1;
    const int kbase = kslice << 10;
    const ushort_t* gA0 = Y + (size_t)yr0 * DOUT + kbase + g * 8;
    const ushort_t* gA1 = Y + (size_t)yr1 * DOUT + kbase + g * 8;
    const ushort_t* Cp = Cb + (size_t)e * SDIM * DOUT + (size_t)(n_tile << 7) * DOUT;
    const ushort_t* gB0 = Cp + (size_t)ar0 * DOUT + kbase + g * 8;
    const ushort_t* gB1 = Cp + (size_t)ar1 * DOUT + kbase + g * 8;
    ushort_t* lA0 = As + c0 * 512; ushort_t* lA1 = As + c1 * 512;
    ushort_t* lB0 = Bs + c0 * 512; ushort_t* lB1 = Bs + c1 * 512;

    const int sw = (quad ^ ((l15 >> 1) & 3)) << 3;

    floatx4 acc[4][4] = {};

    for (int it = 0; it < 32; ++it) {
        GLL16(gA0, lA0); GLL16(gA1, lA1);
        GLL16(gB0, lB0); GLL16(gB1, lB1);
        gA0 += 32; gA1 += 32; gB0 += 32; gB1 += 32;
        __syncthreads();
        short8 af[4], bfr[4];
        #pragma unroll
        for (int i = 0; i < 4; ++i) {
            af[i]  = *(const short8*)&As[(wm + (i << 4) + l15) * 32 + sw];
            bfr[i] = *(const short8*)&Bs[(wn + (i << 4) + l15) * 32 + sw];
        }
        #pragma unroll
        for (int mi = 0; mi < 4; ++mi)
            #pragma unroll
            for (int ni = 0; ni < 4; ++ni)
                acc[mi][ni] = __builtin_amdgcn_mfma_f32_16x16x32_bf16(
                    af[mi], bfr[ni], acc[mi][ni], 0, 0, 0);
        __syncthreads();
    }

    float* Pk = P + (size_t)kslice * (TTOK * SDIM);
    #pragma unroll
    for (int mi = 0; mi < 4; ++mi) {
        #pragma unroll
        for (int rg = 0; rg < 4; ++rg) {
            const int trow = (m_tile << 7) + wm + (mi << 4) + (quad << 2) + rg;
            if (trow < cnt) {
                float* op = Pk + (size_t)(off + trow) * SDIM + (n_tile << 7) + wn;
                #pragma unroll
                for (int ni = 0; ni < 4; ++ni)
                    op[(ni << 4) + l15] = acc[mi][ni][rg];
            }
        }
    }
}

__global__ __launch_bounds__(256)
void reduce4_kernel(const float* __restrict__ P, float* __restrict__ O) {
    const size_t S1 = (size_t)TTOK * SDIM / 4;      // float4 stride per slice
    const int i = blockIdx.x * 256 + threadIdx.x;   // float4 index
    const float4 a = ((const float4*)P)[i];
    const float4 b = ((const float4*)P)[i + S1];
    const float4 c = ((const float4*)P)[i + 2 * S1];
    const float4 d = ((const float4*)P)[i + 3 * S1];
    ((float4*)O)[i] = make_float4(a.x + b.x + c.x + d.x, a.y + b.y + c.y + d.y,
                                  a.z + b.z + c.z + d.z, a.w + b.w + c.w + d.w);
}

// ================= fallback (R1, correct, ws >= 64 MiB) =================
__global__ __launch_bounds__(256, 2)
void gemm1_o(const float* __restrict__ X, const int* __restrict__ counts,
             const float* __restrict__ W, const float* __restrict__ bias,
             ushort_t* __restrict__ Y) {
    __shared__ __align__(16) ushort_t As[128 * LDSS];
    __shared__ __align__(16) ushort_t Bs[128 * LDSS];
    const int bid = blockIdx.x;
    const int e = bid >> 7, r_ = bid & 127;
    const int n_tile = r_ >> 2, m_tile = r_ & 3;
    int off = 0;
    for (int i = 0; i < e; ++i) off += counts[i];
    const int cnt = counts[e];
    const int t = threadIdx.x, wave = t >> 6, lane = t & 63;
    const int wm = (wave & 1) << 6, wn = (wave >> 1) << 6;
    const int l15 = lane & 15, quad = lane >> 4;
    const float* Wp = W + (size_t)e * DOUT * DIN + (size_t)(n_tile << 7) * DIN;
    floatx4 acc[4][4] = {};
    const int srow = t >> 3, scol = (t & 7) << 2;
    for (int k0 = 0; k0 < DIN; k0 += 32) {
        #pragma unroll
        for (int p = 0; p < 4; ++p) {
            const int row = srow + (p << 5);
            int grow = off + (m_tile << 7) + row;
            if (grow >= TTOK) grow = 0;
            const float4 v = *(const float4*)(X + (size_t)grow * DIN + k0 + scol);
            unsigned lo = (unsigned)f2bf(v.x) | ((unsigned)f2bf(v.y) << 16);
            unsigned hi = (unsigned)f2bf(v.z) | ((unsigned)f2bf(v.w) << 16);
            *(uint2*)&As[row * LDSS + scol] = make_uint2(lo, hi);
        }
        #pragma unroll
        for (int p = 0; p < 4; ++p) {
            const int row = srow + (p << 5);
            const float4 v = *(const float4*)(Wp + (size_t)row * DIN + k0 + scol);
            unsigned lo = (unsigned)f2bf(v.x) | ((unsigned)f2bf(v.y) << 16);
            unsigned hi = (unsigned)f2bf(v.z) | ((unsigned)f2bf(v.w) << 16);
            *(uint2*)&Bs[row * LDSS + scol] = make_uint2(lo, hi);
        }
        __syncthreads();
        short8 af[4], bfr[4];
        #pragma unroll
        for (int i = 0; i < 4; ++i) {
            af[i]  = *(const short8*)&As[(wm + (i << 4) + l15) * LDSS + (quad << 3)];
            bfr[i] = *(const short8*)&Bs[(wn + (i << 4) + l15) * LDSS + (quad << 3)];
        }
        #pragma unroll
        for (int mi = 0; mi < 4; ++mi)
            #pragma unroll
            for (int ni = 0; ni < 4; ++ni)
                acc[mi][ni] = __builtin_amdgcn_mfma_f32_16x16x32_bf16(
                    af[mi], bfr[ni], acc[mi][ni], 0, 0, 0);
        __syncthreads();
    }
    float bv[4];
    #pragma unroll
    for (int ni = 0; ni < 4; ++ni)
        bv[ni] = bias[e * DOUT + (n_tile << 7) + wn + (ni << 4) + l15];
    #pragma unroll
    for (int mi = 0; mi < 4; ++mi)
        #pragma unroll
        for (int rg = 0; rg < 4; ++rg) {
            const int trow = (m_tile << 7) + wm + (mi << 4) + (quad << 2) + rg;
            if (trow < cnt) {
                ushort_t* yp = Y + (size_t)(off + trow) * DOUT + (n_tile << 7) + wn;
                #pragma unroll
                for (int ni = 0; ni < 4; ++ni)
                    yp[(ni << 4) + l15] = f2bf(acc[mi][ni][rg] + bv[ni]);
            }
        }
}

__global__ __launch_bounds__(256, 2)
void gemm2_o(const ushort_t* __restrict__ Y, const int* __restrict__ counts,
             const float* __restrict__ C, float* __restrict__ O) {
    __shared__ __align__(16) ushort_t As[128 * LDSS];
    __shared__ __align__(16) ushort_t Bs[128 * LDSS];
    const int bid = blockIdx.x;
    const int e = bid >> 4, r_ = bid & 15;
    const int n_tile = r_ >> 2, m_tile = r_ & 3;
    int off = 0;
    for (int i = 0; i < e; ++i) off += counts[i];
    const int cnt = counts[e];
    const int t = threadIdx.x, wave = t >> 6, lane = t & 63;
    const int wm = (wave & 1) << 6, wn = (wave >> 1) << 6;
    const int l15 = lane & 15, quad = lane >> 4;
    const float* Cp = C + (size_t)e * SDIM * DOUT + (size_t)(n_tile << 7) * DOUT;
    floatx4 acc[4][4] = {};
    const int arow = t >> 2, achk = (t & 3) << 3;
    const int srow = t >> 3, scol = (t & 7) << 2;
    for (int k0 = 0; k0 < DOUT; k0 += 32) {
        #pragma unroll
        for (int p = 0; p < 2; ++p) {
            const int row = arow + (p << 6);
            int grow = off + (m_tile << 7) + row;
            if (grow >= TTOK) grow = 0;
            const short8 v = *(const short8*)(Y + (size_t)grow * DOUT + k0 + achk);
            *(short8*)&As[row * LDSS + achk] = v;
        }
        #pragma unroll
        for (int p = 0; p < 4; ++p) {
            const int row = srow + (p << 5);
            const float4 v = *(const float4*)(Cp + (size_t)row * DOUT + k0 + scol);
            unsigned lo = (unsigned)f2bf(v.x) | ((unsigned)f2bf(v.y) << 16);
            unsigned hi = (unsigned)f2bf(v.z) | ((unsigned)f2bf(v.w) << 16);
            *(uint2*)&Bs[row * LDSS + scol] = make_uint2(lo, hi);
        }
        __syncthreads();
        short8 af[4], bfr[4];
        #pragma unroll
        for (int i = 0; i < 4; ++i) {
            af[i]  = *(const short8*)&As[(wm + (i << 4) + l15) * LDSS + (quad << 3)];
            bfr[i] = *(const short8*)&Bs[(wn + (i << 4) + l15) * LDSS + (quad << 3)];
        }
        #pragma unroll
        for (int mi = 0; mi < 4; ++mi)
            #pragma unroll
            for (int ni = 0; ni < 4; ++ni)
                acc[mi][ni] = __builtin_amdgcn_mfma_f32_16x16x32_bf16(
                    af[mi], bfr[ni], acc[mi][ni], 0, 0, 0);
        __syncthreads();
    }
    #pragma unroll
    for (int mi = 0; mi < 4; ++mi)
        #pragma unroll
        for (int rg = 0; rg < 4; ++rg) {
            const int trow = (m_tile << 7) + wm + (mi << 4) + (quad << 2) + rg;
            if (trow < cnt) {
                float* op = O + (size_t)(off + trow) * SDIM + (n_tile << 7) + wn;
                #pragma unroll
                for (int ni = 0; ni < 4; ++ni)
                    op[(ni << 4) + l15] = acc[mi][ni][rg];
            }
        }
}

extern "C" void kernel_launch(void* const* d_in, const int* in_sizes, int n_in,
                              void* d_out, int out_size, void* d_ws, size_t ws_size,
                              hipStream_t stream) {
    const float* X      = (const float*)d_in[0];
    const int*   counts = (const int*)d_in[1];
    const float* W      = (const float*)d_in[2];
    const float* bias   = (const float*)d_in[3];
    const float* comp   = (const float*)d_in[4];
    float* out = (float*)d_out;

    const size_t OFF_WB = 16777216;     // 16 MiB (after Xb)
    const size_t OFF_CB = 150994944;    // 16+128 MiB
    const size_t OFF_Y  = 218103808;    // +64 MiB
    const size_t NEED   = 285212672;    // 272 MiB total

    if (ws_size >= NEED) {
        ushort_t* Xb = (ushort_t*)d_ws;
        ushort_t* Wb = (ushort_t*)((char*)d_ws + OFF_WB);
        ushort_t* Cb = (ushort_t*)((char*)d_ws + OFF_CB);
        ushort_t* Y  = (ushort_t*)((char*)d_ws + OFF_Y);
        float*    P  = (float*)d_ws;    // 64 MiB, reuses Xb+Wb region after gemm1

        cvt_kernel<<<dim3(4096),  dim3(256), 0, stream>>>(X, Xb, 1048576);
        cvt_kernel<<<dim3(32768), dim3(256), 0, stream>>>(W, Wb, 8388608);
        cvt_kernel<<<dim3(16384), dim3(256), 0, stream>>>(comp, Cb, 4194304);
        gemm1_f<<<dim3(2048), dim3(256), 0, stream>>>(Xb, counts, Wb, bias, Y);
        gemm2_f<<<dim3(1024), dim3(256), 0, stream>>>(Y, counts, Cb, P);
        reduce4_kernel<<<dim3(4096), dim3(256), 0, stream>>>(P, out);
    } else {
        ushort_t* Y = (ushort_t*)d_ws;   // 64 MiB
        gemm1_o<<<dim3(2048), dim3(256), 0, stream>>>(X, counts, W, bias, Y);
        gemm2_o<<<dim3(256),  dim3(256), 0, stream>>>(Y, counts, comp, out);
    }
}